// Round 1
// 359.152 us; speedup vs baseline: 1.0825x; 1.0825x over previous
//
#include <hip/hip_runtime.h>
#include <stdint.h>

#define NB 512
#define SL 1024
#define NT 64

typedef float v4f __attribute__((ext_vector_type(4)));

__device__ __forceinline__ float wave_max6(float v) {
    #pragma unroll
    for (int off = 32; off >= 1; off >>= 1)
        v = fmaxf(v, __shfl_xor(v, off, 64));
    return v;
}
__device__ __forceinline__ float wave_sum_f(float v) {
    #pragma unroll
    for (int off = 32; off >= 1; off >>= 1)
        v += __shfl_xor(v, off, 64);
    return v;
}

// RNE round fp32 -> bf16 (as uint16 in low bits)
__device__ __forceinline__ uint32_t bf16_rne(float x) {
    uint32_t u = __float_as_uint(x);
    return (u + 0x7fffu + ((u >> 16) & 1u)) >> 16;
}

// packed bf16 dot2 accumulate: acc += a.lo*b.lo + a.hi*b.hi
__device__ __forceinline__ void dot2bf(float& acc, uint32_t a, uint32_t b) {
    asm("v_dot2_f32_bf16 %0, %1, %2, %0" : "+v"(acc) : "v"(a), "v"(b));
}
// 3-operand form: d = a.lo*b.lo + a.hi*b.hi + c  (chain starter, avoids re-zero movs)
__device__ __forceinline__ float dot2bf3(uint32_t a, uint32_t b, float c) {
    float d;
    asm("v_dot2_f32_bf16 %0, %1, %2, %3" : "=v"(d) : "v"(a), "v"(b), "v"(c));
    return d;
}

// f32 pair -> packed bf16 dword (src0 -> lo, src1 -> hi), RNE
__device__ __forceinline__ uint32_t cvtpk_bf16(float lo, float hi) {
    uint32_t r;
    asm("v_cvt_pk_bf16_f32 %0, %1, %2" : "=v"(r) : "v"(lo), "v"(hi));
    return r;
}

// DPP row-rotate (row = 16 lanes on gfx9-lineage)
#define ROR1 0x121
#define ROR2 0x122
#define ROR4 0x124
#define ROR8 0x128
template <int CTRL>
__device__ __forceinline__ uint32_t dpp_u(uint32_t x) {
    return (uint32_t)__builtin_amdgcn_mov_dpp((int)x, CTRL, 0xf, 0xf, true);
}

// wave-wide register pull: out[i] = x[addr>>2]
__device__ __forceinline__ float bperm_f(int addr, float x) {
    return __int_as_float(__builtin_amdgcn_ds_bpermute(addr, __float_as_int(x)));
}

// One block (= one wave) per batch row. Forward scan in scaled-exp domain.
// State broadcast is done in-register: DPP rotation gather within each
// 16-lane row + 4 partial dot-products per lane + 3 ds_bpermute cross-row
// reduction. No LDS write/read roundtrip on the critical path.
__global__ void __launch_bounds__(64) crf_fused_kernel(
    const int* __restrict__ tags, const void* __restrict__ mask,
    const float* __restrict__ emit, const float* __restrict__ trans,
    float* __restrict__ out)
{
    const int b = blockIdx.x;
    const int lane = threadIdx.x;
    const float* erow = emit + (size_t)b * SL * NT;
    const int* trow = tags + b * SL;

    // ---------- phase 0: gold-path score + length ----------
    const unsigned char* mb = (const unsigned char*)mask;
    const bool mask_is_i32 = ((mb[1] | mb[2] | mb[3]) == 0);  // dtype sniff

    float acc = 0.f; int cnt = 0;
    #pragma unroll
    for (int j = 0; j < 16; ++j) {
        const int i = lane + 64 * j;
        const int mk = mask_is_i32 ? (((const int*)mask)[(size_t)b * SL + i] != 0)
                                   : (mb[(size_t)b * SL + i] != 0);
        if (mk) {
            const int tg = trow[i];
            float val = erow[(size_t)i * NT + tg];
            if (i > 0) val += trans[trow[i - 1] * NT + tg];
            acc += val; cnt += 1;
        }
    }
    #pragma unroll
    for (int off = 32; off >= 1; off >>= 1) {
        acc += __shfl_xor(acc, off, 64);
        cnt += __shfl_xor(cnt, off, 64);
    }
    const float ts = acc;
    const int len = cnt;

    // ---------- phase 1 setup: index network + pre-permuted exp(trans) ----------
    // Run the gather network once on lane indices; whatever permutation the
    // DPP rotations actually implement, EpkR is packed to match it exactly.
    uint32_t idx = (uint32_t)lane;
    uint32_t i1 = dpp_u<ROR1>(idx);
    uint32_t wIdx[8];
    wIdx[0] = idx | (i1 << 16);
    wIdx[1] = dpp_u<ROR2>(wIdx[0]);
    wIdx[2] = dpp_u<ROR4>(wIdx[0]);
    wIdx[3] = dpp_u<ROR4>(wIdx[1]);
    wIdx[4] = dpp_u<ROR8>(wIdx[0]);
    wIdx[5] = dpp_u<ROR8>(wIdx[1]);
    wIdx[6] = dpp_u<ROR8>(wIdx[2]);
    wIdx[7] = dpp_u<ROR8>(wIdx[3]);

    // EpkR[k][j]: packed bf16 pair of exp(trans[p][lane^16k]) for the two
    // source indices p carried by gather dword j of this lane.
    uint32_t EpkR[4][8];
    #pragma unroll
    for (int k = 0; k < 4; ++k) {
        const int col = lane ^ (k << 4);
        #pragma unroll
        for (int j = 0; j < 8; ++j) {
            const int lo = (int)(wIdx[j] & 0xffffu);
            const int hi = (int)(wIdx[j] >> 16);
            const uint32_t el = bf16_rne(__expf(trans[lo * NT + col]));
            const uint32_t eh = bf16_rne(__expf(trans[hi * NT + col]));
            EpkR[k][j] = el | (eh << 16);
        }
    }

    const int a16 = (lane ^ 16) << 2;   // bpermute byte addresses
    const int a32 = (lane ^ 32) << 2;
    const int a48 = (lane ^ 48) << 2;
    const float fzero = 0.0f;

    float d0 = erow[lane];
    float m0 = wave_max6(d0);
    float v = __expf(d0 - m0);
    float logacc = m0;

    // One scan step: v'[t] = (sum_p v[p]*E[p][t]) * EX,  EX = exp(emit).
    // acc_k(i) = partial over row(i)'s 16 values for output t = i^16k;
    // F[i] = acc0[i] + acc1[i^16] + acc2[i^32] + acc3[i^48]  == full 64-dot.
#define STEP(EX)                                                            \
    {                                                                       \
        const uint32_t n1 = dpp_u<ROR1>(__float_as_uint(v));                \
        const uint32_t w0 = cvtpk_bf16(v, __uint_as_float(n1));             \
        const uint32_t w1 = dpp_u<ROR2>(w0);                                \
        const uint32_t w2 = dpp_u<ROR4>(w0);                                \
        const uint32_t w3 = dpp_u<ROR4>(w1);                                \
        const uint32_t w4 = dpp_u<ROR8>(w0);                                \
        const uint32_t w5 = dpp_u<ROR8>(w1);                                \
        const uint32_t w6 = dpp_u<ROR8>(w2);                                \
        const uint32_t w7 = dpp_u<ROR8>(w3);                                \
        float a0 = dot2bf3(w0, EpkR[0][0], fzero);                          \
        float a1 = dot2bf3(w0, EpkR[1][0], fzero);                          \
        float a2 = dot2bf3(w0, EpkR[2][0], fzero);                          \
        float a3 = dot2bf3(w0, EpkR[3][0], fzero);                          \
        dot2bf(a0, w1, EpkR[0][1]); dot2bf(a1, w1, EpkR[1][1]);             \
        dot2bf(a2, w1, EpkR[2][1]); dot2bf(a3, w1, EpkR[3][1]);             \
        dot2bf(a0, w2, EpkR[0][2]); dot2bf(a1, w2, EpkR[1][2]);             \
        dot2bf(a2, w2, EpkR[2][2]); dot2bf(a3, w2, EpkR[3][2]);             \
        dot2bf(a0, w3, EpkR[0][3]); dot2bf(a1, w3, EpkR[1][3]);             \
        dot2bf(a2, w3, EpkR[2][3]); dot2bf(a3, w3, EpkR[3][3]);             \
        float b0 = dot2bf3(w4, EpkR[0][4], fzero);                          \
        float b1 = dot2bf3(w4, EpkR[1][4], fzero);                          \
        float b2 = dot2bf3(w4, EpkR[2][4], fzero);                          \
        float b3 = dot2bf3(w4, EpkR[3][4], fzero);                          \
        dot2bf(b0, w5, EpkR[0][5]); dot2bf(b1, w5, EpkR[1][5]);             \
        dot2bf(b2, w5, EpkR[2][5]); dot2bf(b3, w5, EpkR[3][5]);             \
        dot2bf(b0, w6, EpkR[0][6]); dot2bf(b1, w6, EpkR[1][6]);             \
        dot2bf(b2, w6, EpkR[2][6]); dot2bf(b3, w6, EpkR[3][6]);             \
        dot2bf(b0, w7, EpkR[0][7]); dot2bf(b1, w7, EpkR[1][7]);             \
        dot2bf(b2, w7, EpkR[2][7]); dot2bf(b3, w7, EpkR[3][7]);             \
        const float acc1 = a1 + b1;                                         \
        const float acc2 = a2 + b2;                                         \
        const float acc3 = a3 + b3;                                         \
        const float x1 = bperm_f(a16, acc1);                                \
        const float x2 = bperm_f(a32, acc2);                                \
        const float x3 = bperm_f(a48, acc3);                                \
        v = (((a0 + b0) + x1) + (x2 + x3)) * (EX);                          \
    }

    const int nstep = len - 1;     // steps i = 1 .. len-1
    const int ngrp = nstep >> 2;   // groups of 4
    int i = 1;

    v4f emq;
    if (ngrp > 0) {
        emq.x = erow[(i + 0) * NT + lane];
        emq.y = erow[(i + 1) * NT + lane];
        emq.z = erow[(i + 2) * NT + lane];
        emq.w = erow[(i + 3) * NT + lane];
    }
    for (int g = 0; g < ngrp; ++g) {
        // emission exps are independent of the chain: issue first
        float ex0 = __expf(emq.x), ex1 = __expf(emq.y);
        float ex2 = __expf(emq.z), ex3 = __expf(emq.w);
        const int ip = i + 4;
        if (g + 1 < ngrp) {  // prefetch next group's emissions
            emq.x = erow[(ip + 0) * NT + lane];
            emq.y = erow[(ip + 1) * NT + lane];
            emq.z = erow[(ip + 2) * NT + lane];
            emq.w = erow[(ip + 3) * NT + lane];
        }
        STEP(ex0)
        STEP(ex1)
        STEP(ex2)
        STEP(ex3)
        // renorm: exact power-of-2 rescale; any lane's exponent is a safe
        // wave-uniform scale (inter-lane spread is bounded).
        {
            uint32_t sb = __builtin_amdgcn_readfirstlane(__float_as_uint(v));
            int ex = (int)((sb >> 23) & 0xffu);
            v *= __uint_as_float((uint32_t)(254 - ex) << 23);  // 2^(127-ex)
            logacc += (float)(ex - 127) * 0.69314718055994530942f;
        }
        i += 4;
    }
    for (; i < len; ++i) {  // remainder (<=3 steps)
        float e = __expf(erow[i * NT + lane]);
        STEP(e)
    }
#undef STEP

    float sum = wave_sum_f(v);
    float log_z = logacc + __logf(sum);
    if (lane == 0) out[b] = -(ts - log_z);
}

extern "C" void kernel_launch(void* const* d_in, const int* in_sizes, int n_in,
                              void* d_out, int out_size, void* d_ws, size_t ws_size,
                              hipStream_t stream) {
    (void)in_sizes; (void)n_in; (void)out_size; (void)d_ws; (void)ws_size;
    const int*   tags  = (const int*)d_in[0];
    const void*  mask  = d_in[1];
    const float* emit  = (const float*)d_in[2];
    const float* trans = (const float*)d_in[3];
    float* out = (float*)d_out;

    crf_fused_kernel<<<dim3(NB), dim3(64), 0, stream>>>(tags, mask, emit, trans, out);
}

// Round 2
// 336.244 us; speedup vs baseline: 1.1562x; 1.0681x over previous
//
#include <hip/hip_runtime.h>
#include <stdint.h>

#define NB 512
#define SL 1024
#define NT 64

typedef float v4f __attribute__((ext_vector_type(4)));

__device__ __forceinline__ float wave_max6(float v) {
    #pragma unroll
    for (int off = 32; off >= 1; off >>= 1)
        v = fmaxf(v, __shfl_xor(v, off, 64));
    return v;
}
__device__ __forceinline__ float wave_sum_f(float v) {
    #pragma unroll
    for (int off = 32; off >= 1; off >>= 1)
        v += __shfl_xor(v, off, 64);
    return v;
}

// RNE round fp32 -> bf16 (as uint16 in low bits)
__device__ __forceinline__ uint32_t bf16_rne(float x) {
    uint32_t u = __float_as_uint(x);
    return (u + 0x7fffu + ((u >> 16) & 1u)) >> 16;
}

// packed bf16 dot2 accumulate: acc += a.lo*b.lo + a.hi*b.hi
__device__ __forceinline__ void dot2bf(float& acc, uint32_t a, uint32_t b) {
    asm("v_dot2_f32_bf16 %0, %1, %2, %0" : "+v"(acc) : "v"(a), "v"(b));
}
// 3-operand form: d = a.lo*b.lo + a.hi*b.hi + c  (chain starter)
__device__ __forceinline__ float dot2bf3(uint32_t a, uint32_t b, float c) {
    float d;
    asm("v_dot2_f32_bf16 %0, %1, %2, %3" : "=v"(d) : "v"(a), "v"(b), "v"(c));
    return d;
}

// f32 pair -> packed bf16 dword (src0 -> lo, src1 -> hi), RNE
__device__ __forceinline__ uint32_t cvtpk_bf16(float lo, float hi) {
    uint32_t r;
    asm("v_cvt_pk_bf16_f32 %0, %1, %2" : "=v"(r) : "v"(lo), "v"(hi));
    return r;
}

// DPP row-rotate (row = 16 lanes)
#define ROR1 0x121
#define ROR2 0x122
#define ROR4 0x124
#define ROR8 0x128
template <int CTRL>
__device__ __forceinline__ uint32_t dpp_u(uint32_t x) {
    return (uint32_t)__builtin_amdgcn_mov_dpp((int)x, CTRL, 0xf, 0xf, true);
}

// gfx950 VALU cross-lane swaps (no LDS pipe, no lgkmcnt).
// Both operands are read-write; swaps 16-lane rows / 32-lane halves
// between the two registers. Direction convention is resolved at runtime
// via an index probe (see below), so either convention is correct.
__device__ __forceinline__ void plswap16_u(uint32_t& a, uint32_t& b) {
    asm("v_permlane16_swap_b32 %0, %1" : "+v"(a), "+v"(b));
}
__device__ __forceinline__ void plswap32_u(uint32_t& a, uint32_t& b) {
    asm("v_permlane32_swap_b32 %0, %1" : "+v"(a), "+v"(b));
}
__device__ __forceinline__ void plswap16_f(float& a, float& b) {
    asm("v_permlane16_swap_b32 %0, %1" : "+v"(a), "+v"(b));
}
__device__ __forceinline__ void plswap32_f(float& a, float& b) {
    asm("v_permlane32_swap_b32 %0, %1" : "+v"(a), "+v"(b));
}

// One block (= one wave) per batch row. Forward scan in scaled-exp domain.
// Fully in-register step: DPP rotation gather (own row's 16 values) +
// 4 partial dot-products per lane + permlane-swap cross-row reduction.
// Zero LDS-pipe traffic on the critical path.
__global__ void __launch_bounds__(64) crf_fused_kernel(
    const int* __restrict__ tags, const void* __restrict__ mask,
    const float* __restrict__ emit, const float* __restrict__ trans,
    float* __restrict__ out)
{
    const int b = blockIdx.x;
    const int lane = threadIdx.x;
    const float* erow = emit + (size_t)b * SL * NT;
    const int* trow = tags + b * SL;

    // ---------- phase 0: gold-path score + length ----------
    const unsigned char* mb = (const unsigned char*)mask;
    const bool mask_is_i32 = ((mb[1] | mb[2] | mb[3]) == 0);  // dtype sniff

    float acc = 0.f; int cnt = 0;
    #pragma unroll
    for (int j = 0; j < 16; ++j) {
        const int i = lane + 64 * j;
        const int mk = mask_is_i32 ? (((const int*)mask)[(size_t)b * SL + i] != 0)
                                   : (mb[(size_t)b * SL + i] != 0);
        if (mk) {
            const int tg = trow[i];
            float val = erow[(size_t)i * NT + tg];
            if (i > 0) val += trans[trow[i - 1] * NT + tg];
            acc += val; cnt += 1;
        }
    }
    #pragma unroll
    for (int off = 32; off >= 1; off >>= 1) {
        acc += __shfl_xor(acc, off, 64);
        cnt += __shfl_xor(cnt, off, 64);
    }
    const float ts = acc;
    const int len = cnt;

    // ---------- phase 1 setup ----------
    // (a) DPP gather network probed on lane indices -> EpkR packing matches
    //     whatever permutation the rotations implement.
    uint32_t idx = (uint32_t)lane;
    uint32_t i1 = dpp_u<ROR1>(idx);
    uint32_t wIdx[8];
    wIdx[0] = idx | (i1 << 16);
    wIdx[1] = dpp_u<ROR2>(wIdx[0]);
    wIdx[2] = dpp_u<ROR4>(wIdx[0]);
    wIdx[3] = dpp_u<ROR4>(wIdx[1]);
    wIdx[4] = dpp_u<ROR8>(wIdx[0]);
    wIdx[5] = dpp_u<ROR8>(wIdx[1]);
    wIdx[6] = dpp_u<ROR8>(wIdx[2]);
    wIdx[7] = dpp_u<ROR8>(wIdx[3]);

    // (b) permlane-swap direction probe on lane indices -> per-lane select
    //     masks valid under either hardware swap convention.
    uint32_t sp = (uint32_t)lane, sq = (uint32_t)lane;
    plswap16_u(sp, sq);
    const bool sel16p = (sp == (uint32_t)(lane ^ 16));  // p-reg carries lane^16's value
    uint32_t tp = (uint32_t)lane, tq = (uint32_t)lane;
    plswap32_u(tp, tq);
    const bool sel32p = (tp == (uint32_t)(lane ^ 32));

    // EpkR[k][j]: packed bf16 pair of exp(trans[p][lane^16k]) for the two
    // source indices p carried by gather dword j of this lane.
    uint32_t EpkR[4][8];
    #pragma unroll
    for (int k = 0; k < 4; ++k) {
        const int col = lane ^ (k << 4);
        #pragma unroll
        for (int j = 0; j < 8; ++j) {
            const int lo = (int)(wIdx[j] & 0xffffu);
            const int hi = (int)(wIdx[j] >> 16);
            const uint32_t el = bf16_rne(__expf(trans[lo * NT + col]));
            const uint32_t eh = bf16_rne(__expf(trans[hi * NT + col]));
            EpkR[k][j] = el | (eh << 16);
        }
    }

    const float fzero = 0.0f;

    float d0 = erow[lane];
    float m0 = wave_max6(d0);
    float v = __expf(d0 - m0);
    float logacc = m0;

    // One scan step: v'[t] = (sum_p v[p]*E[p][t]) * EX,  EX = exp(emit).
    // acc_k(i) = partial over row(i)'s 16 values for output t = i^16k;
    // F[i] = (acc0 + acc1[^16]) + (acc2 + acc3[^16])[^32]  == full 64-dot.
#define STEP(EX)                                                            \
    {                                                                       \
        const uint32_t n1 = dpp_u<ROR1>(__float_as_uint(v));                \
        const uint32_t w0 = cvtpk_bf16(v, __uint_as_float(n1));             \
        const uint32_t w1 = dpp_u<ROR2>(w0);                                \
        const uint32_t w2 = dpp_u<ROR4>(w0);                                \
        const uint32_t w3 = dpp_u<ROR4>(w1);                                \
        const uint32_t w4 = dpp_u<ROR8>(w0);                                \
        const uint32_t w5 = dpp_u<ROR8>(w1);                                \
        const uint32_t w6 = dpp_u<ROR8>(w2);                                \
        const uint32_t w7 = dpp_u<ROR8>(w3);                                \
        float a0 = dot2bf3(w0, EpkR[0][0], fzero);                          \
        float a1 = dot2bf3(w0, EpkR[1][0], fzero);                          \
        float a2 = dot2bf3(w0, EpkR[2][0], fzero);                          \
        float a3 = dot2bf3(w0, EpkR[3][0], fzero);                          \
        dot2bf(a0, w1, EpkR[0][1]); dot2bf(a1, w1, EpkR[1][1]);             \
        dot2bf(a2, w1, EpkR[2][1]); dot2bf(a3, w1, EpkR[3][1]);             \
        dot2bf(a0, w2, EpkR[0][2]); dot2bf(a1, w2, EpkR[1][2]);             \
        dot2bf(a2, w2, EpkR[2][2]); dot2bf(a3, w2, EpkR[3][2]);             \
        dot2bf(a0, w3, EpkR[0][3]); dot2bf(a1, w3, EpkR[1][3]);             \
        dot2bf(a2, w3, EpkR[2][3]); dot2bf(a3, w3, EpkR[3][3]);             \
        float b0 = dot2bf3(w4, EpkR[0][4], fzero);                          \
        float b1 = dot2bf3(w4, EpkR[1][4], fzero);                          \
        float b2 = dot2bf3(w4, EpkR[2][4], fzero);                          \
        float b3 = dot2bf3(w4, EpkR[3][4], fzero);                          \
        dot2bf(b0, w5, EpkR[0][5]); dot2bf(b1, w5, EpkR[1][5]);             \
        dot2bf(b2, w5, EpkR[2][5]); dot2bf(b3, w5, EpkR[3][5]);             \
        dot2bf(b0, w6, EpkR[0][6]); dot2bf(b1, w6, EpkR[1][6]);             \
        dot2bf(b2, w6, EpkR[2][6]); dot2bf(b3, w6, EpkR[3][6]);             \
        dot2bf(b0, w7, EpkR[0][7]); dot2bf(b1, w7, EpkR[1][7]);             \
        dot2bf(b2, w7, EpkR[2][7]); dot2bf(b3, w7, EpkR[3][7]);             \
        float acc1p = a1 + b1, acc1q = acc1p;                               \
        plswap16_f(acc1p, acc1q);                                           \
        const float x1 = sel16p ? acc1p : acc1q;                            \
        float acc3p = a3 + b3, acc3q = acc3p;                               \
        plswap16_f(acc3p, acc3q);                                           \
        const float z3 = sel16p ? acc3p : acc3q;                            \
        float t2p = (a2 + b2) + z3, t2q = t2p;                              \
        plswap32_f(t2p, t2q);                                               \
        const float x23 = sel32p ? t2p : t2q;                               \
        v = (((a0 + b0) + x1) + x23) * (EX);                                \
    }

    const int nstep = len - 1;     // steps i = 1 .. len-1
    const int ngrp = nstep >> 2;   // groups of 4
    int i = 1;

    // Emission prefetch, 3 groups (12 steps) deep: covers ~900-cycle
    // cold-HBM latency even at ~100-cycle steps.
    v4f emq0, emq1, emq2;
#define LOADG(dst, G)                                                   \
    {                                                                   \
        const float* p_ = erow + (size_t)(1 + 4 * (G)) * NT + lane;     \
        dst.x = p_[0];                                                  \
        dst.y = p_[NT];                                                 \
        dst.z = p_[2 * NT];                                             \
        dst.w = p_[3 * NT];                                             \
    }
    if (ngrp > 0) LOADG(emq0, 0)
    if (ngrp > 1) LOADG(emq1, 1)
    if (ngrp > 2) LOADG(emq2, 2)

    for (int g = 0; g < ngrp; ++g) {
        // emission exps are independent of the chain: issue first
        float ex0 = __expf(emq0.x), ex1 = __expf(emq0.y);
        float ex2 = __expf(emq0.z), ex3 = __expf(emq0.w);
        emq0 = emq1;
        emq1 = emq2;
        if (g + 3 < ngrp) LOADG(emq2, g + 3)
        STEP(ex0)
        STEP(ex1)
        STEP(ex2)
        STEP(ex3)
        // renorm: exact power-of-2 rescale; any lane's exponent is a safe
        // wave-uniform scale (inter-lane spread is bounded).
        {
            uint32_t sb = __builtin_amdgcn_readfirstlane(__float_as_uint(v));
            int ex = (int)((sb >> 23) & 0xffu);
            v *= __uint_as_float((uint32_t)(254 - ex) << 23);  // 2^(127-ex)
            logacc += (float)(ex - 127) * 0.69314718055994530942f;
        }
        i += 4;
    }
    for (; i < len; ++i) {  // remainder (<=3 steps)
        float e = __expf(erow[i * NT + lane]);
        STEP(e)
    }
#undef STEP
#undef LOADG

    float sum = wave_sum_f(v);
    float log_z = logacc + __logf(sum);
    if (lane == 0) out[b] = -(ts - log_z);
}

extern "C" void kernel_launch(void* const* d_in, const int* in_sizes, int n_in,
                              void* d_out, int out_size, void* d_ws, size_t ws_size,
                              hipStream_t stream) {
    (void)in_sizes; (void)n_in; (void)out_size; (void)d_ws; (void)ws_size;
    const int*   tags  = (const int*)d_in[0];
    const void*  mask  = d_in[1];
    const float* emit  = (const float*)d_in[2];
    const float* trans = (const float*)d_in[3];
    float* out = (float*)d_out;

    crf_fused_kernel<<<dim3(NB), dim3(64), 0, stream>>>(tags, mask, emit, trans, out);
}